// Round 1
// baseline (2746.378 us; speedup 1.0000x reference)
//
#include <hip/hip_runtime.h>
#include <math.h>

#define MAXDEG 32

#define GF_BIAS    1
#define GF_CSHIFT  2
#define GF_ALPHA   4

__device__ __forceinline__ float lrelu(float v) { return v > 0.f ? v : 0.2f * v; }

// ---------------- CSR-ish build: one slot-scatter per edge ----------------
__global__ void k_scatter(const int* __restrict__ ei, int* cur, int* srcs, int E) {
  int e = blockIdx.x * 256 + threadIdx.x;
  if (e >= E) return;
  int r = ei[e];          // src
  int c = ei[E + e];      // dst
  int slot = atomicAdd(&cur[c], 1);
  if (slot < MAXDEG) srcs[c * MAXDEG + slot] = r;
}

// ---------------- geo distance sum over ei_mol ----------------
__global__ void k_geo(const float* __restrict__ pos, const int* __restrict__ ei,
                      float* gsum, int E) {
  int e = blockIdx.x * 256 + threadIdx.x;
  float d = 0.f;
  if (e < E) {
    int r = ei[e], c = ei[E + e];
    float dx = pos[3*r]   - pos[3*c];
    float dy = pos[3*r+1] - pos[3*c+1];
    float dz = pos[3*r+2] - pos[3*c+2];
    d = sqrtf(dx*dx + dy*dy + dz*dz);
  }
  #pragma unroll
  for (int o = 32; o; o >>= 1) d += __shfl_down(d, o);
  if ((threadIdx.x & 63) == 0) atomicAdd(gsum, d);
}

// ---------------- 128-wide f32 GEMM: C[n,128] = A[n,128] @ W[128,128] ----------------
// flags: GF_BIAS   -> += bias[c] on the stored output
//        GF_CSHIFT -> h += (gscale*gsum)*colsum(W)[c]   (EQGAT scalar x-shift fold)
//        GF_ALPHA  -> also emit aS/aD per-head attention coeffs (segment dot via shfl)
// In-place (C==A) is safe: __syncthreads() separates a row-group's loads from stores,
// and blocks own disjoint row groups.
__global__ __launch_bounds__(256) void k_gemm128(
    const float* __restrict__ A, const float* __restrict__ W,
    const float* __restrict__ bias, float* __restrict__ C,
    const float* __restrict__ asv, const float* __restrict__ adv,
    float* __restrict__ aS, float* __restrict__ aD,
    const float* __restrict__ gsum, float gscale,
    int n, int flags, int fh)
{
  __shared__ float wl[128 * 128];
  const int t = threadIdx.x;
  const int c = t & 127;
  const int half = t >> 7;
  for (int idx = t; idx < 128 * 128; idx += 256) wl[idx] = W[idx];
  __syncthreads();

  float cshift = 0.f;
  if (flags & GF_CSHIFT) {
    float colsum = 0.f;
    for (int k = 0; k < 128; ++k) colsum += wl[k * 128 + c];
    cshift = gscale * gsum[0] * colsum;
  }
  const float bc = (flags & GF_BIAS) ? bias[c] : 0.f;
  float asc = 0.f, adc = 0.f;
  if (flags & GF_ALPHA) { asc = asv[c]; adc = adv[c]; }

  for (int rg = blockIdx.x * 32; rg < n; rg += gridDim.x * 32) {
    const int row0 = rg + half * 16;
    const float* Ab = A + (size_t)row0 * 128;
    float acc[16];
    #pragma unroll
    for (int r = 0; r < 16; ++r) acc[r] = 0.f;
    for (int k4 = 0; k4 < 32; ++k4) {
      const float w0 = wl[(k4*4+0)*128 + c];
      const float w1 = wl[(k4*4+1)*128 + c];
      const float w2 = wl[(k4*4+2)*128 + c];
      const float w3 = wl[(k4*4+3)*128 + c];
      #pragma unroll
      for (int r = 0; r < 16; ++r) {
        const float4 a4 = *(const float4*)(Ab + r*128 + k4*4);
        acc[r] = fmaf(a4.x, w0, acc[r]);
        acc[r] = fmaf(a4.y, w1, acc[r]);
        acc[r] = fmaf(a4.z, w2, acc[r]);
        acc[r] = fmaf(a4.w, w3, acc[r]);
      }
    }
    __syncthreads();   // in-place safety: all loads of this group done before stores
    float vals[16];
    #pragma unroll
    for (int r = 0; r < 16; ++r) {
      vals[r] = acc[r] + cshift;
      C[(size_t)(row0 + r) * 128 + c] = vals[r] + bc;
    }
    if (flags & GF_ALPHA) {
      #pragma unroll
      for (int r = 0; r < 16; ++r) {
        float vs = vals[r] * asc;
        float vd = vals[r] * adc;
        for (int o = fh >> 1; o; o >>= 1) { vs += __shfl_xor(vs, o); vd += __shfl_xor(vd, o); }
        if ((c & (fh - 1)) == 0) {
          const int hd = c / fh;
          aS[(size_t)(row0 + r) * 4 + hd] = vs;
          aD[(size_t)(row0 + r) * 4 + hd] = vd;
        }
      }
    }
  }
}

// ---------------- GAT conv: per-dst softmax over incoming edges + self loop ----------
// mode: 0 = write, 1 = accumulate, 2 = accumulate + relu (layer finalize)
__global__ __launch_bounds__(128) void k_conv(
    const float* __restrict__ h, const float* __restrict__ aS, const float* __restrict__ aD,
    const int* __restrict__ srcs, const int* __restrict__ cnt,
    const float* __restrict__ bias, float* out,
    int fh_shift, int mode)
{
  const int i = blockIdx.x;
  const int t = threadIdx.x;
  const int hd = t >> fh_shift;
  const float aSi = aS[(size_t)i*4 + hd];
  const float aDi = aD[(size_t)i*4 + hd];
  int deg = cnt[i]; if (deg > MAXDEG) deg = MAXDEG;
  const int* sp = srcs + (size_t)i * MAXDEG;

  const float eself = lrelu(aSi + aDi);
  float m = eself;
  for (int j = 0; j < deg; ++j) {
    const int s = sp[j];
    m = fmaxf(m, lrelu(aS[(size_t)s*4 + hd] + aDi));
  }
  float z = 0.f, acc = 0.f;
  for (int j = 0; j < deg; ++j) {
    const int s = sp[j];
    const float e = lrelu(aS[(size_t)s*4 + hd] + aDi);
    const float w = __expf(e - m);
    z += w;
    acc += w * h[(size_t)s*128 + t];
  }
  const float ws = __expf(eself - m);
  z += ws;
  acc += ws * h[(size_t)i*128 + t];

  const float val = acc / (z + 1e-16f) + bias[t];
  const size_t o = (size_t)i*128 + t;
  if (mode == 0) out[o] = val;
  else {
    const float v = out[o] + val;
    out[o] = (mode == 2) ? fmaxf(v, 0.f) : v;
  }
}

// ---------------- output heads: out[r] = {h2[r]@Wy+by, h2[r]@Wa+ba} ----------------
__global__ __launch_bounds__(256) void k_head(
    const float* __restrict__ h2, const float* __restrict__ Wy, const float* __restrict__ by,
    const float* __restrict__ Wa, const float* __restrict__ ba,
    float* __restrict__ out, int n)
{
  const int r = blockIdx.x * 4 + (threadIdx.x >> 6);
  const int L = threadIdx.x & 63;
  if (r >= n) return;
  const float a = h2[(size_t)r*128 + L];
  const float b = h2[(size_t)r*128 + 64 + L];
  float py = a * Wy[L] + b * Wy[64 + L];
  float pa = a * Wa[L] + b * Wa[64 + L];
  #pragma unroll
  for (int o = 32; o; o >>= 1) { py += __shfl_down(py, o); pa += __shfl_down(pa, o); }
  if (L == 0) {
    out[(size_t)r*2]     = py + by[0];
    out[(size_t)r*2 + 1] = pa + ba[0];
  }
}

extern "C" void kernel_launch(void* const* d_in, const int* in_sizes, int n_in,
                              void* d_out, int out_size, void* d_ws, size_t ws_size,
                              hipStream_t stream) {
  const int N = in_sizes[0] / 128;
  const int E = in_sizes[2] / 2;

  const float* x       = (const float*)d_in[0];
  const float* pos     = (const float*)d_in[1];
  const int*   ei_chem = (const int*)d_in[2];
  const int*   ei_cond = (const int*)d_in[3];
  const int*   ei_mol  = (const int*)d_in[4];
  const float* Wp = (const float*)d_in[5];
  const float* bp = (const float*)d_in[6];
  // per-layer params: [Wc,asc,adc,bc, Wd,asd,add,bd, Wm,asm,adm,bm, Wl,bl]
  // input order: 7..20 layer1 (c,d,m,Wl), 21..34 layer2
  const float* Wy = (const float*)d_in[35];
  const float* by = (const float*)d_in[36];
  const float* Wa = (const float*)d_in[37];
  const float* ba = (const float*)d_in[38];

  char* ws = (char*)d_ws;
  size_t off = 0;
  auto alloc = [&](size_t bytes) -> void* {
    void* p = ws + off; off += (bytes + 255) & ~(size_t)255; return p;
  };
  const size_t HB = (size_t)N * 128 * sizeof(float);
  float* H0  = (float*)alloc(HB);
  float* ACC = (float*)alloc(HB);
  float* HR  = (float*)alloc(HB);
  int* SRC[3];
  for (int r = 0; r < 3; ++r) SRC[r] = (int*)alloc((size_t)N * MAXDEG * sizeof(int));
  int*   CUR  = (int*)alloc((size_t)3 * N * sizeof(int));
  float* GSUM = (float*)alloc(256);
  float* AS   = (float*)alloc((size_t)N * 4 * sizeof(float));
  float* AD   = (float*)alloc((size_t)N * 4 * sizeof(float));

  hipMemsetAsync(CUR, 0, (size_t)3 * N * sizeof(int), stream);
  hipMemsetAsync(GSUM, 0, sizeof(float), stream);

  const int egrid = (E + 255) / 256;
  k_scatter<<<egrid, 256, 0, stream>>>(ei_chem, CUR + 0*N, SRC[0], E);
  k_scatter<<<egrid, 256, 0, stream>>>(ei_cond, CUR + 1*N, SRC[1], E);
  k_scatter<<<egrid, 256, 0, stream>>>(ei_mol,  CUR + 2*N, SRC[2], E);
  k_geo<<<egrid, 256, 0, stream>>>(pos, ei_mol, GSUM, E);

  const int GG = 512;  // GEMM grid
  // h0 = x @ Wp + bp
  k_gemm128<<<GG, 256, 0, stream>>>(x, Wp, bp, H0, nullptr, nullptr, nullptr, nullptr,
                                    nullptr, 0.f, N, GF_BIAS, 64);

  auto layer = [&](const float* Hin, float* Acc, int base) {
    const float* Wc  = (const float*)d_in[base+0];
    const float* avc = (const float*)d_in[base+1];
    const float* adc = (const float*)d_in[base+2];
    const float* bc  = (const float*)d_in[base+3];
    const float* Wd  = (const float*)d_in[base+4];
    const float* avd = (const float*)d_in[base+5];
    const float* add = (const float*)d_in[base+6];
    const float* bd  = (const float*)d_in[base+7];
    const float* Wm  = (const float*)d_in[base+8];
    const float* avm = (const float*)d_in[base+9];
    const float* adm = (const float*)d_in[base+10];
    const float* bm  = (const float*)d_in[base+11];
    const float* Wl  = (const float*)d_in[base+12];
    const float* bl  = (const float*)d_in[base+13];

    // EQGAT (mol, heads=4) first: conv writes Acc, then Wl applied in-place
    k_gemm128<<<GG, 256, 0, stream>>>(Hin, Wm, nullptr, HR, avm, adm, AS, AD,
                                      GSUM, 0.1f / (float)E, N, GF_CSHIFT | GF_ALPHA, 32);
    k_conv<<<N, 128, 0, stream>>>(HR, AS, AD, SRC[2], CUR + 2*N, bm, Acc, 5, 0);
    k_gemm128<<<GG, 256, 0, stream>>>(Acc, Wl, bl, Acc, nullptr, nullptr, nullptr, nullptr,
                                      nullptr, 0.f, N, GF_BIAS, 64);
    // chem (heads=2): accumulate
    k_gemm128<<<GG, 256, 0, stream>>>(Hin, Wc, nullptr, HR, avc, adc, AS, AD,
                                      nullptr, 0.f, N, GF_ALPHA, 64);
    k_conv<<<N, 128, 0, stream>>>(HR, AS, AD, SRC[0], CUR + 0*N, bc, Acc, 6, 1);
    // cond (heads=2): accumulate + relu finalize
    k_gemm128<<<GG, 256, 0, stream>>>(Hin, Wd, nullptr, HR, avd, add, AS, AD,
                                      nullptr, 0.f, N, GF_ALPHA, 64);
    k_conv<<<N, 128, 0, stream>>>(HR, AS, AD, SRC[1], CUR + 1*N, bd, Acc, 6, 2);
  };

  layer(H0, ACC, 7);    // h1 = relu(...) in ACC
  layer(ACC, H0, 21);   // h2 = relu(...) in H0

  k_head<<<(N + 3) / 4, 256, 0, stream>>>(H0, Wy, by, Wa, ba, (float*)d_out, N);
}

// Round 2
// 1063.395 us; speedup vs baseline: 2.5827x; 2.5827x over previous
//
#include <hip/hip_runtime.h>
#include <math.h>

typedef short short8 __attribute__((ext_vector_type(8)));
typedef float f32x4 __attribute__((ext_vector_type(4)));

#define MAXDEG 32
#define GF_BIAS   1
#define GF_CSHIFT 2
#define GF_ALPHA  4
#define NFRAG 18432   // 9 nt-tiles * 4 kt * 64 lanes * 8 bf16

__device__ __forceinline__ unsigned short f2bf(float f) {  // RNE f32->bf16
  unsigned u = __float_as_uint(f);
  u += 0x7FFF + ((u >> 16) & 1);
  return (unsigned short)(u >> 16);
}
__device__ __forceinline__ float bf2f(unsigned short s) { return __uint_as_float(((unsigned)s) << 16); }
__device__ __forceinline__ float lrelu(float v) { return v > 0.f ? v : 0.2f * v; }

// ---------------- CSR slot-scatter ----------------
__global__ void k_scatter(const int* __restrict__ ei, int* cur, int* srcs, int E) {
  int e = blockIdx.x * 256 + threadIdx.x;
  if (e >= E) return;
  int r = ei[e];
  int c = ei[E + e];
  int slot = atomicAdd(&cur[c], 1);
  if (slot < MAXDEG) srcs[c * MAXDEG + slot] = r;
}

// ---------------- geo distance sum over ei_mol ----------------
__global__ void k_geo(const float* __restrict__ pos, const int* __restrict__ ei,
                      float* gsum, int E) {
  int e = blockIdx.x * 256 + threadIdx.x;
  float d = 0.f;
  if (e < E) {
    int r = ei[e], c = ei[E + e];
    float dx = pos[3*r]   - pos[3*c];
    float dy = pos[3*r+1] - pos[3*c+1];
    float dz = pos[3*r+2] - pos[3*c+2];
    d = sqrtf(dx*dx + dy*dy + dz*dz);
  }
  #pragma unroll
  for (int o = 32; o; o >>= 1) d += __shfl_down(d, o);
  if ((threadIdx.x & 63) == 0) atomicAdd(gsum, d);
}

// ---------------- weight prep: bf16 hi/lo fragment images + alpha cols + colsums ----
// Fragment layout (matches k_gmm LDS reads): idx = ((nt*4+kt)*64+lane)*8 + j
//   k = kt*32 + (lane>>4)*8 + j, col = nt*16 + (lane&15)
// Extended W' is 128 x 144: cols 0..127 = W, col 128+h = W@as_h (h<4), 132+h = W@ad_h.
struct PrepArgs {
  const float* W[9];
  const float* as_[9];
  const float* ad_[9];
  unsigned short* hi[9];
  unsigned short* lo[9];
  float* csum[9];
  int fh[9];   // 0 = no alpha cols
};

__global__ __launch_bounds__(256) void k_prep(PrepArgs p) {
  const int s = blockIdx.x;
  const int t = threadIdx.x;
  const float* W = p.W[s];
  const int fh = p.fh[s];
  __shared__ float alpha[128 * 8];
  if (t < 128) {
    #pragma unroll
    for (int a = 0; a < 8; ++a) alpha[t * 8 + a] = 0.f;
    if (fh) {
      const int nh = 128 / fh;
      for (int h = 0; h < nh; ++h) {
        float s1 = 0.f, s2 = 0.f;
        for (int c = 0; c < fh; ++c) {
          const float w = W[t * 128 + h * fh + c];
          s1 += w * p.as_[s][h * fh + c];
          s2 += w * p.ad_[s][h * fh + c];
        }
        alpha[t * 8 + h] = s1;
        alpha[t * 8 + 4 + h] = s2;
      }
    }
  }
  __syncthreads();
  for (int idx = t; idx < NFRAG; idx += 256) {
    const int j = idx & 7, lane = (idx >> 3) & 63, kt = (idx >> 9) & 3, nt = idx >> 11;
    const int k = kt * 32 + (lane >> 4) * 8 + j;
    const int col = nt * 16 + (lane & 15);
    float w;
    if (col < 128) w = W[k * 128 + col];
    else if (col < 136) w = alpha[k * 8 + (col - 128)];
    else w = 0.f;
    const unsigned short h = f2bf(w);
    p.hi[s][idx] = h;
    p.lo[s][idx] = f2bf(w - bf2f(h));
  }
  if (t < 136) {
    float cs = 0.f;
    if (t < 128) for (int k = 0; k < 128; ++k) cs += W[k * 128 + t];
    else         for (int k = 0; k < 128; ++k) cs += alpha[k * 8 + (t - 128)];
    p.csum[s][t] = cs;
  }
}

// ---------------- split-bf16 MFMA GEMM: C[n,128] = A[n,128] @ W[128,128] -------------
// + optional alpha cols (aS/aD), colsum shift (EQGAT), bias.
// Each wave: 32 rows (2x 16-row subtiles) x 144 cols. Block = 4 waves = 128 rows/iter.
// In-place (C==A) safe: a wave's loads of its rows complete before its stores; row
// ownership is disjoint across waves and blocks.
__global__ __launch_bounds__(256, 2) void k_gmm(
    const float* __restrict__ A, const unsigned short* __restrict__ Whi,
    const unsigned short* __restrict__ Wlo, const float* __restrict__ csum,
    const float* __restrict__ bias, float* __restrict__ C,
    float* __restrict__ aS, float* __restrict__ aD,
    const float* __restrict__ gsum, float gscale,
    int n, int npad, int flags)
{
  __shared__ unsigned short shi[NFRAG];
  __shared__ unsigned short slo[NFRAG];
  {
    const f32x4* srch = (const f32x4*)Whi;
    const f32x4* srcl = (const f32x4*)Wlo;
    f32x4* dsth = (f32x4*)shi;
    f32x4* dstl = (f32x4*)slo;
    for (int i = threadIdx.x; i < NFRAG / 8; i += 256) { dsth[i] = srch[i]; dstl[i] = srcl[i]; }
  }
  __syncthreads();

  const int wave = threadIdx.x >> 6, lane = threadIdx.x & 63;
  const int m = lane & 15, kq = lane >> 4;
  const float cb = (flags & GF_CSHIFT) ? gscale * gsum[0] : 0.f;

  for (int rb = blockIdx.x * 128; rb < npad; rb += gridDim.x * 128) {
    const int rw = rb + wave * 32;
    short8 ah[2][4], al[2][4];
    #pragma unroll
    for (int sub = 0; sub < 2; ++sub) {
      const int row = rw + sub * 16 + m;
      const bool ok = row < n;
      const float* ap = A + (size_t)row * 128 + kq * 8;
      #pragma unroll
      for (int kt = 0; kt < 4; ++kt) {
        f32x4 x0 = {0.f, 0.f, 0.f, 0.f}, x1 = {0.f, 0.f, 0.f, 0.f};
        if (ok) { x0 = *(const f32x4*)(ap + kt * 32); x1 = *(const f32x4*)(ap + kt * 32 + 4); }
        #pragma unroll
        for (int j = 0; j < 4; ++j) {
          unsigned short h0 = f2bf(x0[j]);
          ah[sub][kt][j] = (short)h0;
          al[sub][kt][j] = (short)f2bf(x0[j] - bf2f(h0));
          unsigned short h1 = f2bf(x1[j]);
          ah[sub][kt][4 + j] = (short)h1;
          al[sub][kt][4 + j] = (short)f2bf(x1[j] - bf2f(h1));
        }
      }
    }
    f32x4 acc[2][9];
    #pragma unroll
    for (int sub = 0; sub < 2; ++sub)
      #pragma unroll
      for (int nt = 0; nt < 9; ++nt) acc[sub][nt] = f32x4{0.f, 0.f, 0.f, 0.f};

    #pragma unroll
    for (int nt = 0; nt < 9; ++nt) {
      #pragma unroll
      for (int kt = 0; kt < 4; ++kt) {
        const int fo = ((nt * 4 + kt) * 64 + lane) * 8;
        const short8 bh = *(const short8*)&shi[fo];
        const short8 bl = *(const short8*)&slo[fo];
        #pragma unroll
        for (int sub = 0; sub < 2; ++sub) {
          acc[sub][nt] = __builtin_amdgcn_mfma_f32_16x16x32_bf16(ah[sub][kt], bh, acc[sub][nt], 0, 0, 0);
          acc[sub][nt] = __builtin_amdgcn_mfma_f32_16x16x32_bf16(al[sub][kt], bh, acc[sub][nt], 0, 0, 0);
          acc[sub][nt] = __builtin_amdgcn_mfma_f32_16x16x32_bf16(ah[sub][kt], bl, acc[sub][nt], 0, 0, 0);
        }
      }
    }
    // epilogue: C/D layout col = lane&15, row = (lane>>4)*4 + r
    #pragma unroll
    for (int sub = 0; sub < 2; ++sub) {
      const int rbase = rw + sub * 16 + kq * 4;
      #pragma unroll
      for (int nt = 0; nt < 8; ++nt) {
        const int col = nt * 16 + m;
        const float cs = (flags & GF_CSHIFT) ? cb * csum[col] : 0.f;
        const float bb = (flags & GF_BIAS) ? bias[col] : 0.f;
        #pragma unroll
        for (int r = 0; r < 4; ++r)
          C[(size_t)(rbase + r) * 128 + col] = acc[sub][nt][r] + cs + bb;
      }
      if ((flags & GF_ALPHA) && m < 8) {
        const float cs = (flags & GF_CSHIFT) ? cb * csum[128 + m] : 0.f;
        #pragma unroll
        for (int r = 0; r < 4; ++r) {
          const float v = acc[sub][8][r] + cs;
          const int row = rbase + r;
          if (m < 4) aS[(size_t)row * 4 + m] = v;
          else       aD[(size_t)row * 4 + (m - 4)] = v;
        }
      }
    }
  }
}

// ---------------- GAT conv: wave per dst node, float2 per lane ----------------
// mode: 0 = write, 1 = accumulate, 2 = accumulate + relu
__global__ __launch_bounds__(256) void k_conv(
    const float* __restrict__ h, const float* __restrict__ aS, const float* __restrict__ aD,
    const int* __restrict__ srcs, const int* __restrict__ cnt,
    const float* __restrict__ bias, float* __restrict__ out,
    int fh_shift, int mode, int n)
{
  const int i = blockIdx.x * 4 + (threadIdx.x >> 6);
  if (i >= n) return;
  const int lane = threadIdx.x & 63;
  const int c0 = lane * 2;
  const int hd = c0 >> fh_shift;
  const float aSi = aS[(size_t)i * 4 + hd];
  const float aDi = aD[(size_t)i * 4 + hd];
  int deg = cnt[i]; if (deg > MAXDEG) deg = MAXDEG;
  const int* sp = srcs + (size_t)i * MAXDEG;

  const float eself = lrelu(aSi + aDi);
  float mx = eself;
  for (int j = 0; j < deg; ++j)
    mx = fmaxf(mx, lrelu(aS[(size_t)sp[j] * 4 + hd] + aDi));
  float z = 0.f, a0 = 0.f, a1 = 0.f;
  for (int j = 0; j < deg; ++j) {
    const int s = sp[j];
    const float w = __expf(lrelu(aS[(size_t)s * 4 + hd] + aDi) - mx);
    z += w;
    const float2 hv = *(const float2*)(h + (size_t)s * 128 + c0);
    a0 += w * hv.x; a1 += w * hv.y;
  }
  const float wsf = __expf(eself - mx);
  z += wsf;
  const float2 hvi = *(const float2*)(h + (size_t)i * 128 + c0);
  a0 += wsf * hvi.x; a1 += wsf * hvi.y;

  const float inv = 1.f / (z + 1e-16f);
  const float2 bb = *(const float2*)(bias + c0);
  const float v0 = a0 * inv + bb.x, v1 = a1 * inv + bb.y;
  float* op = out + (size_t)i * 128 + c0;
  if (mode == 0) { op[0] = v0; op[1] = v1; }
  else {
    float r0 = op[0] + v0, r1 = op[1] + v1;
    if (mode == 2) { r0 = fmaxf(r0, 0.f); r1 = fmaxf(r1, 0.f); }
    op[0] = r0; op[1] = r1;
  }
}

// ---------------- output heads ----------------
__global__ __launch_bounds__(256) void k_head(
    const float* __restrict__ h2, const float* __restrict__ Wy, const float* __restrict__ by,
    const float* __restrict__ Wa, const float* __restrict__ ba,
    float* __restrict__ out, int n)
{
  const int r = blockIdx.x * 4 + (threadIdx.x >> 6);
  const int L = threadIdx.x & 63;
  if (r >= n) return;
  const float a = h2[(size_t)r * 128 + L];
  const float b = h2[(size_t)r * 128 + 64 + L];
  float py = a * Wy[L] + b * Wy[64 + L];
  float pa = a * Wa[L] + b * Wa[64 + L];
  #pragma unroll
  for (int o = 32; o; o >>= 1) { py += __shfl_down(py, o); pa += __shfl_down(pa, o); }
  if (L == 0) {
    out[(size_t)r * 2]     = py + by[0];
    out[(size_t)r * 2 + 1] = pa + ba[0];
  }
}

extern "C" void kernel_launch(void* const* d_in, const int* in_sizes, int n_in,
                              void* d_out, int out_size, void* d_ws, size_t ws_size,
                              hipStream_t stream) {
  const int N = in_sizes[0] / 128;
  const int E = in_sizes[2] / 2;
  const int npad = (N + 127) & ~127;

  const float* x       = (const float*)d_in[0];
  const float* pos     = (const float*)d_in[1];
  const int*   ei_chem = (const int*)d_in[2];
  const int*   ei_cond = (const int*)d_in[3];
  const int*   ei_mol  = (const int*)d_in[4];
  const float* bp = (const float*)d_in[6];
  const float* Wy = (const float*)d_in[35];
  const float* by = (const float*)d_in[36];
  const float* Wa = (const float*)d_in[37];
  const float* ba = (const float*)d_in[38];

  char* ws = (char*)d_ws;
  size_t off = 0;
  auto alloc = [&](size_t bytes) -> void* {
    void* p = ws + off; off += (bytes + 255) & ~(size_t)255; return p;
  };
  const size_t HB = (size_t)npad * 128 * sizeof(float);
  float* H0  = (float*)alloc(HB);
  float* ACC = (float*)alloc(HB);
  float* HR  = (float*)alloc(HB);
  int* SRC[3];
  for (int r = 0; r < 3; ++r) SRC[r] = (int*)alloc((size_t)N * MAXDEG * sizeof(int));
  int*   CUR  = (int*)alloc((size_t)3 * N * sizeof(int));
  float* GSUM = (float*)alloc(256);
  float* AS   = (float*)alloc((size_t)npad * 4 * sizeof(float));
  float* AD   = (float*)alloc((size_t)npad * 4 * sizeof(float));

  // prepped weight images
  PrepArgs pa{};
  const int widx[9] = {5, 7, 11, 15, 19, 21, 25, 29, 33};
  const int fhs[9]  = {0, 64, 64, 32, 0, 64, 64, 32, 0};
  unsigned short *WHI[9], *WLO[9];
  float* CSUM[9];
  for (int s = 0; s < 9; ++s) {
    WHI[s]  = (unsigned short*)alloc(NFRAG * sizeof(unsigned short));
    WLO[s]  = (unsigned short*)alloc(NFRAG * sizeof(unsigned short));
    CSUM[s] = (float*)alloc(144 * sizeof(float));
    pa.W[s] = (const float*)d_in[widx[s]];
    pa.fh[s] = fhs[s];
    pa.as_[s] = fhs[s] ? (const float*)d_in[widx[s] + 1] : nullptr;
    pa.ad_[s] = fhs[s] ? (const float*)d_in[widx[s] + 2] : nullptr;
    pa.hi[s] = WHI[s]; pa.lo[s] = WLO[s]; pa.csum[s] = CSUM[s];
  }

  hipMemsetAsync(CUR, 0, (size_t)3 * N * sizeof(int), stream);
  hipMemsetAsync(GSUM, 0, sizeof(float), stream);

  const int egrid = (E + 255) / 256;
  k_scatter<<<egrid, 256, 0, stream>>>(ei_chem, CUR + 0*N, SRC[0], E);
  k_scatter<<<egrid, 256, 0, stream>>>(ei_cond, CUR + 1*N, SRC[1], E);
  k_scatter<<<egrid, 256, 0, stream>>>(ei_mol,  CUR + 2*N, SRC[2], E);
  k_geo<<<egrid, 256, 0, stream>>>(pos, ei_mol, GSUM, E);
  k_prep<<<9, 256, 0, stream>>>(pa);

  const int GG = 512;
  const float gscale = 0.1f / (float)E;

  // h0 = x @ Wp + bp
  k_gmm<<<GG, 256, 0, stream>>>(x, WHI[0], WLO[0], CSUM[0], bp, H0,
                                nullptr, nullptr, nullptr, 0.f, N, npad, GF_BIAS);

  auto layer = [&](const float* Hin, float* Acc, int base, int s0) {
    const float* bc = (const float*)d_in[base + 3];
    const float* bd = (const float*)d_in[base + 7];
    const float* bm = (const float*)d_in[base + 11];
    const float* bl = (const float*)d_in[base + 13];
    // EQGAT (mol, heads=4): GEMM + alpha + cshift, conv writes Acc, Wl in-place
    k_gmm<<<GG, 256, 0, stream>>>(Hin, WHI[s0+2], WLO[s0+2], CSUM[s0+2], nullptr, HR,
                                  AS, AD, GSUM, gscale, N, npad, GF_CSHIFT | GF_ALPHA);
    k_conv<<<(N + 3) / 4, 256, 0, stream>>>(HR, AS, AD, SRC[2], CUR + 2*N, bm, Acc, 5, 0, N);
    k_gmm<<<GG, 256, 0, stream>>>(Acc, WHI[s0+3], WLO[s0+3], CSUM[s0+3], bl, Acc,
                                  nullptr, nullptr, nullptr, 0.f, N, npad, GF_BIAS);
    // chem (heads=2): accumulate
    k_gmm<<<GG, 256, 0, stream>>>(Hin, WHI[s0+0], WLO[s0+0], CSUM[s0+0], nullptr, HR,
                                  AS, AD, nullptr, 0.f, N, npad, GF_ALPHA);
    k_conv<<<(N + 3) / 4, 256, 0, stream>>>(HR, AS, AD, SRC[0], CUR + 0*N, bc, Acc, 6, 1, N);
    // cond (heads=2): accumulate + relu
    k_gmm<<<GG, 256, 0, stream>>>(Hin, WHI[s0+1], WLO[s0+1], CSUM[s0+1], nullptr, HR,
                                  AS, AD, nullptr, 0.f, N, npad, GF_ALPHA);
    k_conv<<<(N + 3) / 4, 256, 0, stream>>>(HR, AS, AD, SRC[1], CUR + 1*N, bd, Acc, 6, 2, N);
  };

  layer(H0, ACC, 7, 1);    // h1 in ACC
  layer(ACC, H0, 21, 5);   // h2 in H0

  k_head<<<(N + 3) / 4, 256, 0, stream>>>(H0, Wy, by, Wa, ba, (float*)d_out, N);
}